// Round 10
// baseline (136.954 us; speedup 1.0000x reference)
//
#include <hip/hip_runtime.h>
#include <math.h>

#define BATCH   32
#define N_BEADS 16384
#define BEAD_SIZE 16
#define N_ATOMS 100000
#define INV_SQRT2 0.70710678118654752440f
#define SCAN_BLK 256
#define NB 2   // batches per b-group in fusedsum (16 groups -> 2 per XCD)

// ---------- countrec: histogram + rec1[m]={slot,w0,w1,w2} ----------
__global__ void __launch_bounds__(256)
countrec_kernel(const int* __restrict__ atom_idx,
                const int* __restrict__ slot_idx,
                const float* __restrict__ W,
                int* __restrict__ counts,
                float4* __restrict__ rec1, int M)
{
    int m = blockIdx.x * blockDim.x + threadIdx.x;
    if (m >= M) return;
    atomicAdd(&counts[atom_idx[m]], 1);
    int slot = slot_idx[m];
    int h = slot >> 4, l = slot & 15;
    float w0 = W[(0 * N_BEADS + h) * BEAD_SIZE + l];
    float w1 = W[(1 * N_BEADS + h) * BEAD_SIZE + l];
    float w2 = W[(2 * N_BEADS + h) * BEAD_SIZE + l];
    rec1[m] = make_float4(__int_as_float(slot), w0, w1, w2);
}

__global__ void __launch_bounds__(SCAN_BLK)
scan1_kernel(const int* __restrict__ counts, int* __restrict__ off,
             int* __restrict__ bsum, int n)
{
    __shared__ int s[SCAN_BLK];
    int i = blockIdx.x * SCAN_BLK + threadIdx.x;
    int c = (i < n) ? counts[i] : 0;
    s[threadIdx.x] = c;
    __syncthreads();
    int v = c;
    for (int d = 1; d < SCAN_BLK; d <<= 1) {
        int t = (threadIdx.x >= d) ? s[threadIdx.x - d] : 0;
        __syncthreads();
        v += t;
        s[threadIdx.x] = v;
        __syncthreads();
    }
    if (i < n) off[i] = v - c;
    if (threadIdx.x == SCAN_BLK - 1) bsum[blockIdx.x] = v;
}

// finalize offsets; zero cursor; rec_a = {cnt, off, scal} (used by fallback sum)
__global__ void __launch_bounds__(256)
scan3_kernel(int* __restrict__ off, const int* __restrict__ bsum,
             const int* __restrict__ counts, const float* __restrict__ scal,
             int* __restrict__ cursor2, float4* __restrict__ rec_a, int n)
{
    __shared__ int red[256];
    int j = blockIdx.x;
    int partial = 0;
    for (int i = threadIdx.x; i < j; i += 256) partial += bsum[i];
    red[threadIdx.x] = partial;
    __syncthreads();
    for (int d = 128; d > 0; d >>= 1) {
        if ((int)threadIdx.x < d) red[threadIdx.x] += red[threadIdx.x + d];
        __syncthreads();
    }
    int bpref = red[0];
    int i = j * 256 + threadIdx.x;
    if (i >= n) return;
    int o = off[i] + bpref;
    off[i] = o;
    cursor2[i] = 0;
    rec_a[i] = make_float4(__int_as_float(counts[i]), __int_as_float(o),
                           scal[i], 0.f);
}

// fill: the ONE random scatter — per-m records into CSR order.
// recA[pos]={slot,w0,w1,w2}  recB[pos]={2cs, 2s^2, scal, atom(bits)}
__global__ void __launch_bounds__(256)
fill_kernel(const int* __restrict__ atom_idx, const int* __restrict__ off,
            const float4* __restrict__ rec1, const float* __restrict__ ang,
            const float* __restrict__ scal, int* __restrict__ cursor2,
            float4* __restrict__ recA, float4* __restrict__ recB, int M)
{
    int m = blockIdx.x * blockDim.x + threadIdx.x;
    if (m >= M) return;
    int a = atom_idx[m];
    int k = atomicAdd(&cursor2[a], 1);
    int pos = off[a] + k;
    float sa, ca;
    __sincosf(ang[m], &sa, &ca);
    recA[pos] = rec1[m];
    recB[pos] = make_float4(2.f * ca * sa, 2.f * sa * sa, scal[a],
                            __int_as_float(a));
}

// pp: pack {p1,p2,P} per (b,bead) into one 48B record -> ~1.5 cache lines
// per random gather instead of 3+.
__global__ void __launch_bounds__(256)
pp_kernel(const float* __restrict__ p1, const float* __restrict__ p2,
          const float* __restrict__ P, float* __restrict__ pp)
{
    int t = blockIdx.x * 256 + threadIdx.x;
    if (t >= BATCH * N_BEADS) return;
    const float* a = p1 + (size_t)t * 3;
    const float* b = p2 + (size_t)t * 3;
    const float* c = P  + (size_t)t * 3;
    float* o = pp + (size_t)t * 12;
    ((float4*)o)[0] = make_float4(a[0], a[1], a[2], b[0]);
    ((float4*)o)[1] = make_float4(b[1], b[2], c[0], c[1]);
    ((float4*)o)[2] = make_float4(c[2], 0.f, 0.f, 0.f);
}

// ---------- pass 1: rot (m-order, near-sequential bead reads) ----------
__global__ void __launch_bounds__(256)
rot_kernel(const float* __restrict__ p1, const float* __restrict__ p2,
           const float4* __restrict__ rec1, float* __restrict__ out_rot, int M)
{
    int b = blockIdx.y;
    int mbase = blockIdx.x * 256;
    int m = mbase + threadIdx.x;
    __shared__ float sbuf[768];

    float rx = 0.f, ry = 0.f, rz = 0.f;
    if (m < M) {
        float4 r = rec1[m];
        int slot = __float_as_int(r.x);
        int h = slot >> 4;
        const float* p1p = p1 + ((size_t)b * N_BEADS + h) * 3;
        const float* p2p = p2 + ((size_t)b * N_BEADS + h) * 3;
        float a1x = p1p[0], a1y = p1p[1], a1z = p1p[2];
        float a2x = p2p[0], a2y = p2p[1], a2z = p2p[2];
        float cxx = (a1y * a2z - a1z * a2y) * INV_SQRT2;
        float cyy = (a1z * a2x - a1x * a2z) * INV_SQRT2;
        float czz = (a1x * a2y - a1y * a2x) * INV_SQRT2;
        rx = r.y * a1x + r.z * a2x + r.w * cxx;
        ry = r.y * a1y + r.z * a2y + r.w * cyy;
        rz = r.y * a1z + r.z * a2z + r.w * czz;
        float inv = rsqrtf(rx * rx + ry * ry + rz * rz);
        rx *= inv; ry *= inv; rz *= inv;
    }
    sbuf[threadIdx.x * 3 + 0] = rx;
    sbuf[threadIdx.x * 3 + 1] = ry;
    sbuf[threadIdx.x * 3 + 2] = rz;
    __syncthreads();

    int nm = M - mbase; if (nm > 256) nm = 256;
    int nf = nm * 3;
    size_t base = ((size_t)b * M + mbase) * 3;
    if (((base * sizeof(float)) & 15) == 0) {
        int nf4 = nf >> 2;
        float4* dst = (float4*)(out_rot + base);
        if ((int)threadIdx.x < nf4)
            dst[threadIdx.x] = ((const float4*)sbuf)[threadIdx.x];
        int done = nf4 << 2;
        int rr = nf - done;
        if ((int)threadIdx.x < rr)
            out_rot[base + done + threadIdx.x] = sbuf[done + threadIdx.x];
    } else if (m < M) {
        out_rot[base + threadIdx.x * 3 + 0] = rx;
        out_rot[base + threadIdx.x * 3 + 1] = ry;
        out_rot[base + threadIdx.x * 3 + 2] = rz;
    }
}

// ---------- pass 2: contribution compute + wave-segmented reduction ----------
// Thread = CSR position; NB=2 batches each. aid is sorted along pos, so each
// atom's contributions are contiguous lanes: segmented shuffle-scan, then the
// segment tail writes. Tails whose segment head is inside the wave (found via
// ballot of head flags) own the atom's ENTIRE global sum -> direct store;
// wave-straddling pieces (~2/wave) atomicAdd onto memset-zeroed out_atoms.
__global__ void __launch_bounds__(256)
fusedsum_kernel(const float4* __restrict__ recA,
                const float4* __restrict__ recB,
                const float* __restrict__ pp,
                float* __restrict__ out_atoms, int M)
{
    int bg = blockIdx.x;                 // 0..15 ; XCD = bg & 7
    int p0 = blockIdx.y * 256;
    int tid = threadIdx.x;
    int pos = p0 + tid;
    int lane = tid & 63;
    int b0 = bg * NB;

    bool act = pos < M;
    int posc = act ? pos : (M - 1);

    float4 rA = recA[posc];
    float4 rB = recB[posc];
    int aid = __float_as_int(rB.w);
    float s = rB.z;
    int h = __float_as_int(rA.x) >> 4;

    float ox[NB], oy[NB], oz[NB];
    const size_t rstride = (size_t)N_BEADS * 12;
    const float* base0 = pp + (size_t)b0 * rstride + (size_t)h * 12;
#pragma unroll
    for (int i = 0; i < NB; ++i) {
        const float* r = base0 + i * rstride;
        float4 v0 = ((const float4*)r)[0];
        float4 v1 = ((const float4*)r)[1];
        float  Pz = r[8];
        float a1x = v0.x, a1y = v0.y, a1z = v0.z;
        float a2x = v0.w, a2y = v1.x, a2z = v1.y;
        float Px = v1.z, Py = v1.w;

        float cxx = (a1y * a2z - a1z * a2y) * INV_SQRT2;
        float cyy = (a1z * a2x - a1x * a2z) * INV_SQRT2;
        float czz = (a1x * a2y - a1y * a2x) * INV_SQRT2;
        float rx = rA.y * a1x + rA.z * a2x + rA.w * cxx;
        float ry = rA.y * a1y + rA.z * a2y + rA.w * cyy;
        float rz = rA.y * a1z + rA.z * a2z + rA.w * czz;
        float inv = rsqrtf(rx * rx + ry * ry + rz * rz);
        rx *= inv; ry *= inv; rz *= inv;

        // Rodrigues: v' = v + 2cs (r x v) + 2s^2 (r x (r x v)), v = p1
        float ux = ry * a1z - rz * a1y;
        float uy = rz * a1x - rx * a1z;
        float uz = rx * a1y - ry * a1x;
        float wx = ry * uz - rz * uy;
        float wy = rz * ux - rx * uz;
        float wz = rx * uy - ry * ux;
        float vx = s * (a1x + rB.x * ux + rB.y * wx) + Px;
        float vy = s * (a1y + rB.x * uy + rB.y * wy) + Py;
        float vz = s * (a1z + rB.x * uz + rB.y * wz) + Pz;
        ox[i] = act ? vx : 0.f;
        oy[i] = act ? vy : 0.f;
        oz[i] = act ? vz : 0.f;
    }

    // neighbor atom ids (memory read at wave edges)
    int aid_prev = __shfl_up(aid, 1, 64);
    int aid_next = __shfl_down(aid, 1, 64);
    if (lane == 0)  aid_prev = (posc > 0) ? __float_as_int(recB[posc - 1].w) : -1;
    if (lane == 63) aid_next = (pos + 1 < M) ? __float_as_int(recB[pos + 1].w) : -1;
    bool headf     = (aid != aid_prev);
    bool real_tail = (aid != aid_next);

    // segmented inclusive scan (aid sorted -> same-aid test suffices)
#pragma unroll
    for (int d = 1; d < 64; d <<= 1) {
        int aidu = __shfl_up(aid, d, 64);
        float t0 = __shfl_up(ox[0], d, 64);
        float t1 = __shfl_up(oy[0], d, 64);
        float t2 = __shfl_up(oz[0], d, 64);
        float t3 = __shfl_up(ox[1], d, 64);
        float t4 = __shfl_up(oy[1], d, 64);
        float t5 = __shfl_up(oz[1], d, 64);
        if (lane >= d && aidu == aid) {
            ox[0] += t0; oy[0] += t1; oz[0] += t2;
            ox[1] += t3; oy[1] += t4; oz[1] += t5;
        }
    }

    unsigned long long headmask = __ballot(headf);
    unsigned long long below = (lane == 63) ? ~0ull
                                            : ((1ull << (lane + 1)) - 1ull);
    unsigned long long hm = headmask & below;   // heads at or below my lane

    bool flush = real_tail || (lane == 63);
    if (flush) {
        bool direct = real_tail && (hm != 0ull);  // global head+tail in this wave
#pragma unroll
        for (int i = 0; i < NB; ++i) {
            float* op = out_atoms + ((size_t)(b0 + i) * N_ATOMS + aid) * 3;
            if (direct) {
                op[0] = ox[i]; op[1] = oy[i]; op[2] = oz[i];
            } else {
                atomicAdd(op + 0, ox[i]);
                atomicAdd(op + 1, oy[i]);
                atomicAdd(op + 2, oz[i]);
            }
        }
    }
}

// ---------- mid fallback: round-7 sum (atom-parallel recompute) ----------
__global__ void __launch_bounds__(256)
sum_r7_kernel(const float4* __restrict__ rec_a,
              const float4* __restrict__ recA,
              const float4* __restrict__ recB,
              const float* __restrict__ p1,
              const float* __restrict__ p2,
              const float* __restrict__ P,
              float* __restrict__ out_atoms)
{
    int beta = blockIdx.x;
    int xcd  = beta & 7;
    int ablk = beta >> 3;
    int b0 = xcd * 4;
    int abase = ablk * 256;
    int a = abase + threadIdx.x;

    float ax[4], ay[4], az[4];
#pragma unroll
    for (int i = 0; i < 4; ++i) { ax[i] = 0.f; ay[i] = 0.f; az[i] = 0.f; }

    if (a < N_ATOMS) {
        float4 ra = rec_a[a];
        int cnt = __float_as_int(ra.x);
        int o   = __float_as_int(ra.y);
        float s = ra.z;
        const size_t bstride = (size_t)N_BEADS * 3;
        const float* p1b = p1 + (size_t)b0 * bstride;
        const float* p2b = p2 + (size_t)b0 * bstride;
        const float* Pb  = P  + (size_t)b0 * bstride;
        for (int k = 0; k < cnt; ++k) {
            int pos = o + k;
            float4 rA = recA[pos];
            float4 rB = recB[pos];
            size_t hoff = (size_t)(__float_as_int(rA.x) >> 4) * 3;
#pragma unroll
            for (int i = 0; i < 4; ++i) {
                const float* p1p = p1b + i * bstride + hoff;
                const float* p2p = p2b + i * bstride + hoff;
                float a1x = p1p[0], a1y = p1p[1], a1z = p1p[2];
                float a2x = p2p[0], a2y = p2p[1], a2z = p2p[2];
                float cxx = (a1y * a2z - a1z * a2y) * INV_SQRT2;
                float cyy = (a1z * a2x - a1x * a2z) * INV_SQRT2;
                float czz = (a1x * a2y - a1y * a2x) * INV_SQRT2;
                float rx = rA.y * a1x + rA.z * a2x + rA.w * cxx;
                float ry = rA.y * a1y + rA.z * a2y + rA.w * cyy;
                float rz = rA.y * a1z + rA.z * a2z + rA.w * czz;
                float inv = rsqrtf(rx * rx + ry * ry + rz * rz);
                rx *= inv; ry *= inv; rz *= inv;
                float ux = ry * a1z - rz * a1y;
                float uy = rz * a1x - rx * a1z;
                float uz = rx * a1y - ry * a1x;
                float wx = ry * uz - rz * uy;
                float wy = rz * ux - rx * uz;
                float wz = rx * uy - ry * ux;
                const float* Pp = Pb + i * bstride + hoff;
                ax[i] += s * (a1x + rB.x * ux + rB.y * wx) + Pp[0];
                ay[i] += s * (a1y + rB.x * uy + rB.y * wy) + Pp[1];
                az[i] += s * (a1z + rB.x * uz + rB.y * wz) + Pp[2];
            }
        }
    }

    __shared__ float sbuf[768];
    int na = N_ATOMS - abase; if (na > 256) na = 256;
    int nf = na * 3;
    int nf4 = nf >> 2;
    int done = nf4 << 2;
    int rem = nf - done;
#pragma unroll
    for (int i = 0; i < 4; ++i) {
        __syncthreads();
        sbuf[threadIdx.x * 3 + 0] = ax[i];
        sbuf[threadIdx.x * 3 + 1] = ay[i];
        sbuf[threadIdx.x * 3 + 2] = az[i];
        __syncthreads();
        size_t base = ((size_t)(b0 + i) * N_ATOMS + abase) * 3;
        float4* dst = (float4*)(out_atoms + base);
        if ((int)threadIdx.x < nf4)
            dst[threadIdx.x] = ((const float4*)sbuf)[threadIdx.x];
        if ((int)threadIdx.x < rem)
            out_atoms[base + done + threadIdx.x] = sbuf[done + threadIdx.x];
    }
}

// ---------- last-resort fallback: atomic scatter ----------
__global__ void __launch_bounds__(256)
backmap_fallback(const float* __restrict__ P, const float* __restrict__ p1,
                 const float* __restrict__ p2, const float* __restrict__ W,
                 const float* __restrict__ ang, const float* __restrict__ scal,
                 const int* __restrict__ slot_idx, const int* __restrict__ atom_idx,
                 float* __restrict__ out_atoms, float* __restrict__ out_rot, int M)
{
    int t = blockIdx.x * blockDim.x + threadIdx.x;
    if (t >= BATCH * M) return;
    int b = t / M; int m = t - b * M;
    int slot = slot_idx[m]; int h = slot >> 4; int l = slot & 15;
    int atom = atom_idx[m];
    const float* p1p = p1 + ((size_t)b * N_BEADS + h) * 3;
    const float* p2p = p2 + ((size_t)b * N_BEADS + h) * 3;
    float a1x = p1p[0], a1y = p1p[1], a1z = p1p[2];
    float a2x = p2p[0], a2y = p2p[1], a2z = p2p[2];
    float cx = (a1y * a2z - a1z * a2y) * INV_SQRT2;
    float cy = (a1z * a2x - a1x * a2z) * INV_SQRT2;
    float cz = (a1x * a2y - a1y * a2x) * INV_SQRT2;
    float w0 = W[(0 * N_BEADS + h) * BEAD_SIZE + l];
    float w1 = W[(1 * N_BEADS + h) * BEAD_SIZE + l];
    float w2 = W[(2 * N_BEADS + h) * BEAD_SIZE + l];
    float rx = w0 * a1x + w1 * a2x + w2 * cx;
    float ry = w0 * a1y + w1 * a2y + w2 * cy;
    float rz = w0 * a1z + w1 * a2z + w2 * cz;
    float inv = rsqrtf(rx * rx + ry * ry + rz * rz);
    rx *= inv; ry *= inv; rz *= inv;
    float* ro = out_rot + (size_t)t * 3;
    ro[0] = rx; ro[1] = ry; ro[2] = rz;
    float sa, ca; __sincosf(ang[m], &sa, &ca);
    float A = 2.f * ca * sa, Bc = 2.f * sa * sa;
    float ux = ry * a1z - rz * a1y;
    float uy = rz * a1x - rx * a1z;
    float uz = rx * a1y - ry * a1x;
    float wx = ry * uz - rz * uy;
    float wy = rz * ux - rx * uz;
    float wz = rx * uy - ry * ux;
    float s = scal[atom];
    const float* Pp = P + ((size_t)b * N_BEADS + h) * 3;
    float* op = out_atoms + ((size_t)b * N_ATOMS + atom) * 3;
    atomicAdd(op + 0, s * (a1x + A * ux + Bc * wx) + Pp[0]);
    atomicAdd(op + 1, s * (a1y + A * uy + Bc * wy) + Pp[1]);
    atomicAdd(op + 2, s * (a1z + A * uz + Bc * wz) + Pp[2]);
}

extern "C" void kernel_launch(void* const* d_in, const int* in_sizes, int n_in,
                              void* d_out, int out_size, void* d_ws, size_t ws_size,
                              hipStream_t stream) {
    const float* P    = (const float*)d_in[0];
    const float* p1   = (const float*)d_in[1];
    const float* p2   = (const float*)d_in[2];
    const float* W    = (const float*)d_in[3];
    const float* ang  = (const float*)d_in[4];
    const float* scal = (const float*)d_in[5];
    const int* slot_idx = (const int*)d_in[6];
    const int* atom_idx = (const int*)d_in[7];

    int M = in_sizes[6];
    float* out_atoms = (float*)d_out;
    float* out_rot   = out_atoms + (size_t)BATCH * N_ATOMS * 3;

    int nblk   = (N_ATOMS + SCAN_BLK - 1) / SCAN_BLK;   // 391
    int nchunk = (M + 255) / 256;                       // 544

    // ws: counts|off|cursor2 (N_ATOMS int) | bsum(512 int)
    //     rec1[M] f4 | recA[M] f4 | recB[M] f4 | rec_a[N_ATOMS] f4 | pp[B*NB_BEADS*12] f
    size_t intpre   = (size_t)N_ATOMS * 4 * 3 + 512 * 4;   // 16B-aligned
    size_t need_mid = intpre + (size_t)M * 16 * 3 + (size_t)N_ATOMS * 16;
    size_t need_new = need_mid + (size_t)BATCH * N_BEADS * 12 * 4;

    if (ws_size >= need_mid) {
        int* counts  = (int*)d_ws;
        int* off     = counts + N_ATOMS;
        int* cursor2 = off + N_ATOMS;
        int* bsum    = cursor2 + N_ATOMS;
        float4* rec1  = (float4*)((char*)d_ws + intpre);
        float4* recA  = rec1 + M;
        float4* recB  = recA + M;
        float4* rec_a = recB + M;
        float*  pp    = (float*)(rec_a + N_ATOMS);

        hipMemsetAsync(counts, 0, (size_t)N_ATOMS * sizeof(int), stream);
        countrec_kernel<<<nchunk, 256, 0, stream>>>(
            atom_idx, slot_idx, W, counts, rec1, M);
        scan1_kernel<<<nblk, SCAN_BLK, 0, stream>>>(counts, off, bsum, N_ATOMS);
        scan3_kernel<<<nblk, 256, 0, stream>>>(off, bsum, counts, scal,
                                               cursor2, rec_a, N_ATOMS);
        fill_kernel<<<nchunk, 256, 0, stream>>>(
            atom_idx, off, rec1, ang, scal, cursor2, recA, recB, M);

        dim3 g1(nchunk, BATCH);
        rot_kernel<<<g1, 256, 0, stream>>>(p1, p2, rec1, out_rot, M);

        if (ws_size >= need_new) {
            hipMemsetAsync(out_atoms, 0,
                           (size_t)BATCH * N_ATOMS * 3 * sizeof(float), stream);
            pp_kernel<<<(BATCH * N_BEADS + 255) / 256, 256, 0, stream>>>(
                p1, p2, P, pp);
            dim3 gf(BATCH / NB, nchunk);     // x = b-group -> XCD pin
            fusedsum_kernel<<<gf, 256, 0, stream>>>(
                recA, recB, pp, out_atoms, M);
        } else {
            int abps = (N_ATOMS + 255) / 256;
            sum_r7_kernel<<<abps * (BATCH / 4), 256, 0, stream>>>(
                rec_a, recA, recB, p1, p2, P, out_atoms);
        }
        return;
    }

    // last resort: atomic scatter
    hipMemsetAsync(out_atoms, 0, (size_t)BATCH * N_ATOMS * 3 * sizeof(float), stream);
    int total = BATCH * M;
    backmap_fallback<<<(total + 255) / 256, 256, 0, stream>>>(
        P, p1, p2, W, ang, scal, slot_idx, atom_idx,
        out_atoms, out_rot, M);
}

// Round 11
// 98.481 us; speedup vs baseline: 1.3907x; 1.3907x over previous
//
#include <hip/hip_runtime.h>
#include <math.h>

#define BATCH   32
#define N_BEADS 16384
#define BEAD_SIZE 16
#define N_ATOMS 100000
#define INV_SQRT2 0.70710678118654752440f
#define SCAN_BLK 256

// ---------- countrec: histogram + rec1[m]={slot,w0,w1,w2} ----------
__global__ void __launch_bounds__(256)
countrec_kernel(const int* __restrict__ atom_idx,
                const int* __restrict__ slot_idx,
                const float* __restrict__ W,
                int* __restrict__ counts,
                float4* __restrict__ rec1, int M)
{
    int m = blockIdx.x * blockDim.x + threadIdx.x;
    if (m >= M) return;
    atomicAdd(&counts[atom_idx[m]], 1);
    int slot = slot_idx[m];
    int h = slot >> 4, l = slot & 15;
    float w0 = W[(0 * N_BEADS + h) * BEAD_SIZE + l];
    float w1 = W[(1 * N_BEADS + h) * BEAD_SIZE + l];
    float w2 = W[(2 * N_BEADS + h) * BEAD_SIZE + l];
    rec1[m] = make_float4(__int_as_float(slot), w0, w1, w2);
}

__global__ void __launch_bounds__(SCAN_BLK)
scan1_kernel(const int* __restrict__ counts, int* __restrict__ off,
             int* __restrict__ bsum, int n)
{
    __shared__ int s[SCAN_BLK];
    int i = blockIdx.x * SCAN_BLK + threadIdx.x;
    int c = (i < n) ? counts[i] : 0;
    s[threadIdx.x] = c;
    __syncthreads();
    int v = c;
    for (int d = 1; d < SCAN_BLK; d <<= 1) {
        int t = (threadIdx.x >= d) ? s[threadIdx.x - d] : 0;
        __syncthreads();
        v += t;
        s[threadIdx.x] = v;
        __syncthreads();
    }
    if (i < n) off[i] = v - c;
    if (threadIdx.x == SCAN_BLK - 1) bsum[blockIdx.x] = v;
}

// finalize offsets; zero cursor; rec_a = {cnt, off, 0, 0}
__global__ void __launch_bounds__(256)
scan3_kernel(int* __restrict__ off, const int* __restrict__ bsum,
             const int* __restrict__ counts,
             int* __restrict__ cursor2, float4* __restrict__ rec_a, int n)
{
    __shared__ int red[256];
    int j = blockIdx.x;
    int partial = 0;
    for (int i = threadIdx.x; i < j; i += 256) partial += bsum[i];
    red[threadIdx.x] = partial;
    __syncthreads();
    for (int d = 128; d > 0; d >>= 1) {
        if ((int)threadIdx.x < d) red[threadIdx.x] += red[threadIdx.x + d];
        __syncthreads();
    }
    int bpref = red[0];
    int i = j * 256 + threadIdx.x;
    if (i >= n) return;
    int o = off[i] + bpref;
    off[i] = o;
    cursor2[i] = 0;
    rec_a[i] = make_float4(__int_as_float(counts[i]), __int_as_float(o),
                           0.f, 0.f);
}

// fill2: m-order. The ONLY scatter is csr_m[pos]=m (4B).
// recM2[m] = {2*cos*sin, 2*sin^2, scal[atom]} written SEQUENTIALLY.
__global__ void __launch_bounds__(256)
fill2_kernel(const int* __restrict__ atom_idx, const int* __restrict__ off,
             const float* __restrict__ ang, const float* __restrict__ scal,
             int* __restrict__ cursor2, int* __restrict__ csr_m,
             float4* __restrict__ recM2, int M)
{
    int m = blockIdx.x * blockDim.x + threadIdx.x;
    if (m >= M) return;
    int a = atom_idx[m];
    int k = atomicAdd(&cursor2[a], 1);
    csr_m[off[a] + k] = m;
    float sa, ca;
    __sincosf(ang[m], &sa, &ca);
    recM2[m] = make_float4(2.f * ca * sa, 2.f * sa * sa, scal[a], 0.f);
}

// ---------- pass 1: m-order contribution compute (monotone h gathers) ----------
// grid (mchunk, 8). bg covers b in [4bg, 4bg+4). Computes rot AND the full
// per-(b,m) contribution; both stored via LDS-staged float4 (coalesced).
__global__ void __launch_bounds__(256)
mcontrib_kernel(const float4* __restrict__ rec1,
                const float4* __restrict__ recM2,
                const float* __restrict__ p1,
                const float* __restrict__ p2,
                const float* __restrict__ P,
                float* __restrict__ out_rot,   // (B, M, 3)
                float* __restrict__ cM,        // (B, M, 3)
                int M)
{
    int bg = blockIdx.y;             // 0..7
    int mbase = blockIdx.x * 256;
    int m = mbase + threadIdx.x;
    int b0 = bg * 4;
    bool act = m < M;
    int mc = act ? m : (M - 1);

    float4 r1 = rec1[mc];
    float4 r2 = recM2[mc];
    int h = __float_as_int(r1.x) >> 4;
    float A = r2.x, Bc = r2.y, s = r2.z;
    size_t hoff = (size_t)h * 3;

    __shared__ float sbuf[768];
    int nm = M - mbase; if (nm > 256) nm = 256;
    int nf = nm * 3;
    int nf4 = nf >> 2;
    int done = nf4 << 2;
    int rem = nf - done;

#pragma unroll
    for (int i = 0; i < 4; ++i) {
        int b = b0 + i;
        const size_t bb = (size_t)b * N_BEADS * 3;
        const float* p1p = p1 + bb + hoff;
        const float* p2p = p2 + bb + hoff;
        const float* Pp  = P  + bb + hoff;
        float a1x = p1p[0], a1y = p1p[1], a1z = p1p[2];
        float a2x = p2p[0], a2y = p2p[1], a2z = p2p[2];

        float cxx = (a1y * a2z - a1z * a2y) * INV_SQRT2;
        float cyy = (a1z * a2x - a1x * a2z) * INV_SQRT2;
        float czz = (a1x * a2y - a1y * a2x) * INV_SQRT2;
        float rx = r1.y * a1x + r1.z * a2x + r1.w * cxx;
        float ry = r1.y * a1y + r1.z * a2y + r1.w * cyy;
        float rz = r1.y * a1z + r1.z * a2z + r1.w * czz;
        float inv = rsqrtf(rx * rx + ry * ry + rz * rz);
        rx *= inv; ry *= inv; rz *= inv;

        // stage + write rot
        __syncthreads();
        sbuf[threadIdx.x * 3 + 0] = rx;
        sbuf[threadIdx.x * 3 + 1] = ry;
        sbuf[threadIdx.x * 3 + 2] = rz;
        __syncthreads();
        {
            size_t base = ((size_t)b * M + mbase) * 3;
            float4* dst = (float4*)(out_rot + base);   // 16B-aligned when M%? handled below
            if (((base & 3) == 0)) {
                if ((int)threadIdx.x < nf4)
                    dst[threadIdx.x] = ((const float4*)sbuf)[threadIdx.x];
                if ((int)threadIdx.x < rem)
                    out_rot[base + done + threadIdx.x] = sbuf[done + threadIdx.x];
            } else if (act) {
                out_rot[base + threadIdx.x * 3 + 0] = rx;
                out_rot[base + threadIdx.x * 3 + 1] = ry;
                out_rot[base + threadIdx.x * 3 + 2] = rz;
            }
        }

        // Rodrigues contribution: v' = v + A (r x v) + Bc (r x (r x v)), v = p1
        float ux = ry * a1z - rz * a1y;
        float uy = rz * a1x - rx * a1z;
        float uz = rx * a1y - ry * a1x;
        float wx = ry * uz - rz * uy;
        float wy = rz * ux - rx * uz;
        float wz = rx * uy - ry * ux;
        float ox = s * (a1x + A * ux + Bc * wx) + Pp[0];
        float oy = s * (a1y + A * uy + Bc * wy) + Pp[1];
        float oz = s * (a1z + A * uz + Bc * wz) + Pp[2];

        // stage + write contribution
        __syncthreads();
        sbuf[threadIdx.x * 3 + 0] = ox;
        sbuf[threadIdx.x * 3 + 1] = oy;
        sbuf[threadIdx.x * 3 + 2] = oz;
        __syncthreads();
        {
            size_t base = ((size_t)b * M + mbase) * 3;
            float4* dst = (float4*)(cM + base);
            if (((base & 3) == 0)) {
                if ((int)threadIdx.x < nf4)
                    dst[threadIdx.x] = ((const float4*)sbuf)[threadIdx.x];
                if ((int)threadIdx.x < rem)
                    cM[base + done + threadIdx.x] = sbuf[done + threadIdx.x];
            } else if (act) {
                cM[base + threadIdx.x * 3 + 0] = ox;
                cM[base + threadIdx.x * 3 + 1] = oy;
                cM[base + threadIdx.x * 3 + 2] = oz;
            }
        }
    }
}

// ---------- pass 2: round-4-proven sum. One b per block; cM b-slice (1.67MB)
// is L2-resident on its XCD (b = xcd + 8*round). csr_m read sequentially;
// the ONLY random read is cM[b][m] (12B) within the slice. Writes every atom. ----------
__global__ void __launch_bounds__(256)
sum2_kernel(const float4* __restrict__ rec_a,
            const int* __restrict__ csr_m,
            const float* __restrict__ cM,
            float* __restrict__ out_atoms, int M, int abps)
{
    int beta = blockIdx.x;
    int xcd  = beta & 7;
    int j    = beta >> 3;
    int round = j / abps;                 // 0..3
    int ablk  = j - round * abps;
    int b = xcd + 8 * round;
    int abase = ablk * 256;
    int a = abase + threadIdx.x;

    float ax = 0.f, ay = 0.f, az = 0.f;
    if (a < N_ATOMS) {
        float4 ra = rec_a[a];
        int cnt = __float_as_int(ra.x);
        int o   = __float_as_int(ra.y);
        const float* cb = cM + (size_t)b * M * 3;
        for (int k = 0; k < cnt; ++k) {
            int m = csr_m[o + k];
            const float* cp = cb + (size_t)m * 3;
            ax += cp[0]; ay += cp[1]; az += cp[2];
        }
    }
    __shared__ float sbuf[768];
    sbuf[threadIdx.x * 3 + 0] = ax;
    sbuf[threadIdx.x * 3 + 1] = ay;
    sbuf[threadIdx.x * 3 + 2] = az;
    __syncthreads();

    int na = N_ATOMS - abase; if (na > 256) na = 256;
    int nf = na * 3;
    size_t base = ((size_t)b * N_ATOMS + abase) * 3;   // 16B-aligned
    int nf4 = nf >> 2;
    float4* dst = (float4*)(out_atoms + base);
    if ((int)threadIdx.x < nf4)
        dst[threadIdx.x] = ((const float4*)sbuf)[threadIdx.x];
    int done = nf4 << 2;
    int rem = nf - done;
    if ((int)threadIdx.x < rem)
        out_atoms[base + done + threadIdx.x] = sbuf[done + threadIdx.x];
}

// ---------- last-resort fallback: atomic scatter ----------
__global__ void __launch_bounds__(256)
backmap_fallback(const float* __restrict__ P, const float* __restrict__ p1,
                 const float* __restrict__ p2, const float* __restrict__ W,
                 const float* __restrict__ ang, const float* __restrict__ scal,
                 const int* __restrict__ slot_idx, const int* __restrict__ atom_idx,
                 float* __restrict__ out_atoms, float* __restrict__ out_rot, int M)
{
    int t = blockIdx.x * blockDim.x + threadIdx.x;
    if (t >= BATCH * M) return;
    int b = t / M; int m = t - b * M;
    int slot = slot_idx[m]; int h = slot >> 4; int l = slot & 15;
    int atom = atom_idx[m];
    const float* p1p = p1 + ((size_t)b * N_BEADS + h) * 3;
    const float* p2p = p2 + ((size_t)b * N_BEADS + h) * 3;
    float a1x = p1p[0], a1y = p1p[1], a1z = p1p[2];
    float a2x = p2p[0], a2y = p2p[1], a2z = p2p[2];
    float cx = (a1y * a2z - a1z * a2y) * INV_SQRT2;
    float cy = (a1z * a2x - a1x * a2z) * INV_SQRT2;
    float cz = (a1x * a2y - a1y * a2x) * INV_SQRT2;
    float w0 = W[(0 * N_BEADS + h) * BEAD_SIZE + l];
    float w1 = W[(1 * N_BEADS + h) * BEAD_SIZE + l];
    float w2 = W[(2 * N_BEADS + h) * BEAD_SIZE + l];
    float rx = w0 * a1x + w1 * a2x + w2 * cx;
    float ry = w0 * a1y + w1 * a2y + w2 * cy;
    float rz = w0 * a1z + w1 * a2z + w2 * cz;
    float inv = rsqrtf(rx * rx + ry * ry + rz * rz);
    rx *= inv; ry *= inv; rz *= inv;
    float* ro = out_rot + (size_t)t * 3;
    ro[0] = rx; ro[1] = ry; ro[2] = rz;
    float sa, ca; __sincosf(ang[m], &sa, &ca);
    float A = 2.f * ca * sa, Bc = 2.f * sa * sa;
    float ux = ry * a1z - rz * a1y;
    float uy = rz * a1x - rx * a1z;
    float uz = rx * a1y - ry * a1x;
    float wx = ry * uz - rz * uy;
    float wy = rz * ux - rx * uz;
    float wz = rx * uy - ry * ux;
    float s = scal[atom];
    const float* Pp = P + ((size_t)b * N_BEADS + h) * 3;
    float* op = out_atoms + ((size_t)b * N_ATOMS + atom) * 3;
    atomicAdd(op + 0, s * (a1x + A * ux + Bc * wx) + Pp[0]);
    atomicAdd(op + 1, s * (a1y + A * uy + Bc * wy) + Pp[1]);
    atomicAdd(op + 2, s * (a1z + A * uz + Bc * wz) + Pp[2]);
}

extern "C" void kernel_launch(void* const* d_in, const int* in_sizes, int n_in,
                              void* d_out, int out_size, void* d_ws, size_t ws_size,
                              hipStream_t stream) {
    const float* P    = (const float*)d_in[0];
    const float* p1   = (const float*)d_in[1];
    const float* p2   = (const float*)d_in[2];
    const float* W    = (const float*)d_in[3];
    const float* ang  = (const float*)d_in[4];
    const float* scal = (const float*)d_in[5];
    const int* slot_idx = (const int*)d_in[6];
    const int* atom_idx = (const int*)d_in[7];

    int M = in_sizes[6];
    float* out_atoms = (float*)d_out;
    float* out_rot   = out_atoms + (size_t)BATCH * N_ATOMS * 3;

    int nblk   = (N_ATOMS + SCAN_BLK - 1) / SCAN_BLK;   // 391
    int nchunk = (M + 255) / 256;                       // 544

    // ws: counts|off|cursor2 (N_ATOMS int) | bsum(512 int)
    //     rec1[M] f4 | recM2[M] f4 | rec_a[N_ATOMS] f4 | csr_m[M] int | cM[B*M*3] f
    size_t intpre = (size_t)N_ATOMS * 4 * 3 + 512 * 4;   // 16B-aligned
    size_t need   = intpre + (size_t)M * 16 * 2 + (size_t)N_ATOMS * 16
                  + (size_t)M * 4 + (size_t)BATCH * M * 3 * 4;

    if (ws_size >= need) {
        int* counts  = (int*)d_ws;
        int* off     = counts + N_ATOMS;
        int* cursor2 = off + N_ATOMS;
        int* bsum    = cursor2 + N_ATOMS;
        float4* rec1  = (float4*)((char*)d_ws + intpre);
        float4* recM2 = rec1 + M;
        float4* rec_a = recM2 + M;
        int*    csr_m = (int*)(rec_a + N_ATOMS);
        float*  cM    = (float*)(csr_m + M);

        hipMemsetAsync(counts, 0, (size_t)N_ATOMS * sizeof(int), stream);
        countrec_kernel<<<nchunk, 256, 0, stream>>>(
            atom_idx, slot_idx, W, counts, rec1, M);
        scan1_kernel<<<nblk, SCAN_BLK, 0, stream>>>(counts, off, bsum, N_ATOMS);
        scan3_kernel<<<nblk, 256, 0, stream>>>(off, bsum, counts,
                                               cursor2, rec_a, N_ATOMS);
        fill2_kernel<<<nchunk, 256, 0, stream>>>(
            atom_idx, off, ang, scal, cursor2, csr_m, recM2, M);

        dim3 gm(nchunk, 8);
        mcontrib_kernel<<<gm, 256, 0, stream>>>(
            rec1, recM2, p1, p2, P, out_rot, cM, M);

        int abps = (N_ATOMS + 255) / 256;                // 391
        sum2_kernel<<<abps * BATCH, 256, 0, stream>>>(
            rec_a, csr_m, cM, out_atoms, M, abps);
        return;
    }

    // last resort: atomic scatter
    hipMemsetAsync(out_atoms, 0, (size_t)BATCH * N_ATOMS * 3 * sizeof(float), stream);
    int total = BATCH * M;
    backmap_fallback<<<(total + 255) / 256, 256, 0, stream>>>(
        P, p1, p2, W, ang, scal, slot_idx, atom_idx,
        out_atoms, out_rot, M);
}

// Round 12
// 98.266 us; speedup vs baseline: 1.3937x; 1.0022x over previous
//
#include <hip/hip_runtime.h>
#include <math.h>

#define BATCH   32
#define N_BEADS 16384
#define BEAD_SIZE 16
#define N_ATOMS 100000
#define INV_SQRT2 0.70710678118654752440f
#define SCAN_BLK 256

// ---------- zero: replaces hipMemsetAsync(counts) — rocclr fillBuffer was 55 µs ----------
__global__ void __launch_bounds__(256)
zero_kernel(int* __restrict__ p, int n)
{
    int i = blockIdx.x * 256 + threadIdx.x;
    if (i < n) p[i] = 0;
}

// ---------- countrec: histogram + rec1[m]={slot,w0,w1,w2} ----------
__global__ void __launch_bounds__(256)
countrec_kernel(const int* __restrict__ atom_idx,
                const int* __restrict__ slot_idx,
                const float* __restrict__ W,
                int* __restrict__ counts,
                float4* __restrict__ rec1, int M)
{
    int m = blockIdx.x * blockDim.x + threadIdx.x;
    if (m >= M) return;
    atomicAdd(&counts[atom_idx[m]], 1);
    int slot = slot_idx[m];
    int h = slot >> 4, l = slot & 15;
    float w0 = W[(0 * N_BEADS + h) * BEAD_SIZE + l];
    float w1 = W[(1 * N_BEADS + h) * BEAD_SIZE + l];
    float w2 = W[(2 * N_BEADS + h) * BEAD_SIZE + l];
    rec1[m] = make_float4(__int_as_float(slot), w0, w1, w2);
}

__global__ void __launch_bounds__(SCAN_BLK)
scan1_kernel(const int* __restrict__ counts, int* __restrict__ off,
             int* __restrict__ bsum, int n)
{
    __shared__ int s[SCAN_BLK];
    int i = blockIdx.x * SCAN_BLK + threadIdx.x;
    int c = (i < n) ? counts[i] : 0;
    s[threadIdx.x] = c;
    __syncthreads();
    int v = c;
    for (int d = 1; d < SCAN_BLK; d <<= 1) {
        int t = (threadIdx.x >= d) ? s[threadIdx.x - d] : 0;
        __syncthreads();
        v += t;
        s[threadIdx.x] = v;
        __syncthreads();
    }
    if (i < n) off[i] = v - c;
    if (threadIdx.x == SCAN_BLK - 1) bsum[blockIdx.x] = v;
}

// finalize offsets; zero cursor; rec_a = {cnt, off, 0, 0}
__global__ void __launch_bounds__(256)
scan3_kernel(int* __restrict__ off, const int* __restrict__ bsum,
             const int* __restrict__ counts,
             int* __restrict__ cursor2, float4* __restrict__ rec_a, int n)
{
    __shared__ int red[256];
    int j = blockIdx.x;
    int partial = 0;
    for (int i = threadIdx.x; i < j; i += 256) partial += bsum[i];
    red[threadIdx.x] = partial;
    __syncthreads();
    for (int d = 128; d > 0; d >>= 1) {
        if ((int)threadIdx.x < d) red[threadIdx.x] += red[threadIdx.x + d];
        __syncthreads();
    }
    int bpref = red[0];
    int i = j * 256 + threadIdx.x;
    if (i >= n) return;
    int o = off[i] + bpref;
    off[i] = o;
    cursor2[i] = 0;
    rec_a[i] = make_float4(__int_as_float(counts[i]), __int_as_float(o),
                           0.f, 0.f);
}

// fill2: m-order. The ONLY scatter is csr_m[pos]=m (4B).
// recM2[m] = {2*cos*sin, 2*sin^2, scal[atom]} written SEQUENTIALLY.
__global__ void __launch_bounds__(256)
fill2_kernel(const int* __restrict__ atom_idx, const int* __restrict__ off,
             const float* __restrict__ ang, const float* __restrict__ scal,
             int* __restrict__ cursor2, int* __restrict__ csr_m,
             float4* __restrict__ recM2, int M)
{
    int m = blockIdx.x * blockDim.x + threadIdx.x;
    if (m >= M) return;
    int a = atom_idx[m];
    int k = atomicAdd(&cursor2[a], 1);
    csr_m[off[a] + k] = m;
    float sa, ca;
    __sincosf(ang[m], &sa, &ca);
    recM2[m] = make_float4(2.f * ca * sa, 2.f * sa * sa, scal[a], 0.f);
}

// ---------- pass 1: m-order contribution compute (monotone h gathers) ----------
// grid (mchunk, 8). bg covers b in [4bg, 4bg+4). Computes rot AND the full
// per-(b,m) contribution; both stored via LDS-staged float4 (coalesced).
__global__ void __launch_bounds__(256)
mcontrib_kernel(const float4* __restrict__ rec1,
                const float4* __restrict__ recM2,
                const float* __restrict__ p1,
                const float* __restrict__ p2,
                const float* __restrict__ P,
                float* __restrict__ out_rot,   // (B, M, 3)
                float* __restrict__ cM,        // (B, M, 3)
                int M)
{
    int bg = blockIdx.y;             // 0..7
    int mbase = blockIdx.x * 256;
    int m = mbase + threadIdx.x;
    int b0 = bg * 4;
    bool act = m < M;
    int mc = act ? m : (M - 1);

    float4 r1 = rec1[mc];
    float4 r2 = recM2[mc];
    int h = __float_as_int(r1.x) >> 4;
    float A = r2.x, Bc = r2.y, s = r2.z;
    size_t hoff = (size_t)h * 3;

    __shared__ float sbuf[768];
    int nm = M - mbase; if (nm > 256) nm = 256;
    int nf = nm * 3;
    int nf4 = nf >> 2;
    int done = nf4 << 2;
    int rem = nf - done;

#pragma unroll
    for (int i = 0; i < 4; ++i) {
        int b = b0 + i;
        const size_t bb = (size_t)b * N_BEADS * 3;
        const float* p1p = p1 + bb + hoff;
        const float* p2p = p2 + bb + hoff;
        const float* Pp  = P  + bb + hoff;
        float a1x = p1p[0], a1y = p1p[1], a1z = p1p[2];
        float a2x = p2p[0], a2y = p2p[1], a2z = p2p[2];

        float cxx = (a1y * a2z - a1z * a2y) * INV_SQRT2;
        float cyy = (a1z * a2x - a1x * a2z) * INV_SQRT2;
        float czz = (a1x * a2y - a1y * a2x) * INV_SQRT2;
        float rx = r1.y * a1x + r1.z * a2x + r1.w * cxx;
        float ry = r1.y * a1y + r1.z * a2y + r1.w * cyy;
        float rz = r1.y * a1z + r1.z * a2z + r1.w * czz;
        float inv = rsqrtf(rx * rx + ry * ry + rz * rz);
        rx *= inv; ry *= inv; rz *= inv;

        // stage + write rot
        __syncthreads();
        sbuf[threadIdx.x * 3 + 0] = rx;
        sbuf[threadIdx.x * 3 + 1] = ry;
        sbuf[threadIdx.x * 3 + 2] = rz;
        __syncthreads();
        {
            size_t base = ((size_t)b * M + mbase) * 3;
            float4* dst = (float4*)(out_rot + base);
            if (((base & 3) == 0)) {
                if ((int)threadIdx.x < nf4)
                    dst[threadIdx.x] = ((const float4*)sbuf)[threadIdx.x];
                if ((int)threadIdx.x < rem)
                    out_rot[base + done + threadIdx.x] = sbuf[done + threadIdx.x];
            } else if (act) {
                out_rot[base + threadIdx.x * 3 + 0] = rx;
                out_rot[base + threadIdx.x * 3 + 1] = ry;
                out_rot[base + threadIdx.x * 3 + 2] = rz;
            }
        }

        // Rodrigues contribution: v' = v + A (r x v) + Bc (r x (r x v)), v = p1
        float ux = ry * a1z - rz * a1y;
        float uy = rz * a1x - rx * a1z;
        float uz = rx * a1y - ry * a1x;
        float wx = ry * uz - rz * uy;
        float wy = rz * ux - rx * uz;
        float wz = rx * uy - ry * ux;
        float ox = s * (a1x + A * ux + Bc * wx) + Pp[0];
        float oy = s * (a1y + A * uy + Bc * wy) + Pp[1];
        float oz = s * (a1z + A * uz + Bc * wz) + Pp[2];

        // stage + write contribution
        __syncthreads();
        sbuf[threadIdx.x * 3 + 0] = ox;
        sbuf[threadIdx.x * 3 + 1] = oy;
        sbuf[threadIdx.x * 3 + 2] = oz;
        __syncthreads();
        {
            size_t base = ((size_t)b * M + mbase) * 3;
            float4* dst = (float4*)(cM + base);
            if (((base & 3) == 0)) {
                if ((int)threadIdx.x < nf4)
                    dst[threadIdx.x] = ((const float4*)sbuf)[threadIdx.x];
                if ((int)threadIdx.x < rem)
                    cM[base + done + threadIdx.x] = sbuf[done + threadIdx.x];
            } else if (act) {
                cM[base + threadIdx.x * 3 + 0] = ox;
                cM[base + threadIdx.x * 3 + 1] = oy;
                cM[base + threadIdx.x * 3 + 2] = oz;
            }
        }
    }
}

// ---------- pass 2: sum. One b per block; cM b-slice (1.67MB) is L2-resident
// on its XCD (b = xcd + 8*round). csr_m read sequentially; the ONLY random
// read is cM[b][m] (12B) within the slice. Writes every atom (no memset). ----------
__global__ void __launch_bounds__(256)
sum2_kernel(const float4* __restrict__ rec_a,
            const int* __restrict__ csr_m,
            const float* __restrict__ cM,
            float* __restrict__ out_atoms, int M, int abps)
{
    int beta = blockIdx.x;
    int xcd  = beta & 7;
    int j    = beta >> 3;
    int round = j / abps;                 // 0..3
    int ablk  = j - round * abps;
    int b = xcd + 8 * round;
    int abase = ablk * 256;
    int a = abase + threadIdx.x;

    float ax = 0.f, ay = 0.f, az = 0.f;
    if (a < N_ATOMS) {
        float4 ra = rec_a[a];
        int cnt = __float_as_int(ra.x);
        int o   = __float_as_int(ra.y);
        const float* cb = cM + (size_t)b * M * 3;
        for (int k = 0; k < cnt; ++k) {
            int m = csr_m[o + k];
            const float* cp = cb + (size_t)m * 3;
            ax += cp[0]; ay += cp[1]; az += cp[2];
        }
    }
    __shared__ float sbuf[768];
    sbuf[threadIdx.x * 3 + 0] = ax;
    sbuf[threadIdx.x * 3 + 1] = ay;
    sbuf[threadIdx.x * 3 + 2] = az;
    __syncthreads();

    int na = N_ATOMS - abase; if (na > 256) na = 256;
    int nf = na * 3;
    size_t base = ((size_t)b * N_ATOMS + abase) * 3;   // 16B-aligned
    int nf4 = nf >> 2;
    float4* dst = (float4*)(out_atoms + base);
    if ((int)threadIdx.x < nf4)
        dst[threadIdx.x] = ((const float4*)sbuf)[threadIdx.x];
    int done = nf4 << 2;
    int rem = nf - done;
    if ((int)threadIdx.x < rem)
        out_atoms[base + done + threadIdx.x] = sbuf[done + threadIdx.x];
}

// ---------- last-resort fallback: atomic scatter ----------
__global__ void __launch_bounds__(256)
backmap_fallback(const float* __restrict__ P, const float* __restrict__ p1,
                 const float* __restrict__ p2, const float* __restrict__ W,
                 const float* __restrict__ ang, const float* __restrict__ scal,
                 const int* __restrict__ slot_idx, const int* __restrict__ atom_idx,
                 float* __restrict__ out_atoms, float* __restrict__ out_rot, int M)
{
    int t = blockIdx.x * blockDim.x + threadIdx.x;
    if (t >= BATCH * M) return;
    int b = t / M; int m = t - b * M;
    int slot = slot_idx[m]; int h = slot >> 4; int l = slot & 15;
    int atom = atom_idx[m];
    const float* p1p = p1 + ((size_t)b * N_BEADS + h) * 3;
    const float* p2p = p2 + ((size_t)b * N_BEADS + h) * 3;
    float a1x = p1p[0], a1y = p1p[1], a1z = p1p[2];
    float a2x = p2p[0], a2y = p2p[1], a2z = p2p[2];
    float cx = (a1y * a2z - a1z * a2y) * INV_SQRT2;
    float cy = (a1z * a2x - a1x * a2z) * INV_SQRT2;
    float cz = (a1x * a2y - a1y * a2x) * INV_SQRT2;
    float w0 = W[(0 * N_BEADS + h) * BEAD_SIZE + l];
    float w1 = W[(1 * N_BEADS + h) * BEAD_SIZE + l];
    float w2 = W[(2 * N_BEADS + h) * BEAD_SIZE + l];
    float rx = w0 * a1x + w1 * a2x + w2 * cx;
    float ry = w0 * a1y + w1 * a2y + w2 * cy;
    float rz = w0 * a1z + w1 * a2z + w2 * cz;
    float inv = rsqrtf(rx * rx + ry * ry + rz * rz);
    rx *= inv; ry *= inv; rz *= inv;
    float* ro = out_rot + (size_t)t * 3;
    ro[0] = rx; ro[1] = ry; ro[2] = rz;
    float sa, ca; __sincosf(ang[m], &sa, &ca);
    float A = 2.f * ca * sa, Bc = 2.f * sa * sa;
    float ux = ry * a1z - rz * a1y;
    float uy = rz * a1x - rx * a1z;
    float uz = rx * a1y - ry * a1x;
    float wx = ry * uz - rz * uy;
    float wy = rz * ux - rx * uz;
    float wz = rx * uy - ry * ux;
    float s = scal[atom];
    const float* Pp = P + ((size_t)b * N_BEADS + h) * 3;
    float* op = out_atoms + ((size_t)b * N_ATOMS + atom) * 3;
    atomicAdd(op + 0, s * (a1x + A * ux + Bc * wx) + Pp[0]);
    atomicAdd(op + 1, s * (a1y + A * uy + Bc * wy) + Pp[1]);
    atomicAdd(op + 2, s * (a1z + A * uz + Bc * wz) + Pp[2]);
}

extern "C" void kernel_launch(void* const* d_in, const int* in_sizes, int n_in,
                              void* d_out, int out_size, void* d_ws, size_t ws_size,
                              hipStream_t stream) {
    const float* P    = (const float*)d_in[0];
    const float* p1   = (const float*)d_in[1];
    const float* p2   = (const float*)d_in[2];
    const float* W    = (const float*)d_in[3];
    const float* ang  = (const float*)d_in[4];
    const float* scal = (const float*)d_in[5];
    const int* slot_idx = (const int*)d_in[6];
    const int* atom_idx = (const int*)d_in[7];

    int M = in_sizes[6];
    float* out_atoms = (float*)d_out;
    float* out_rot   = out_atoms + (size_t)BATCH * N_ATOMS * 3;

    int nblk   = (N_ATOMS + SCAN_BLK - 1) / SCAN_BLK;   // 391
    int nchunk = (M + 255) / 256;                       // 544

    // ws: counts|off|cursor2 (N_ATOMS int) | bsum(512 int)
    //     rec1[M] f4 | recM2[M] f4 | rec_a[N_ATOMS] f4 | csr_m[M] int | cM[B*M*3] f
    size_t intpre = (size_t)N_ATOMS * 4 * 3 + 512 * 4;   // 16B-aligned
    size_t need   = intpre + (size_t)M * 16 * 2 + (size_t)N_ATOMS * 16
                  + (size_t)M * 4 + (size_t)BATCH * M * 3 * 4;

    if (ws_size >= need) {
        int* counts  = (int*)d_ws;
        int* off     = counts + N_ATOMS;
        int* cursor2 = off + N_ATOMS;
        int* bsum    = cursor2 + N_ATOMS;
        float4* rec1  = (float4*)((char*)d_ws + intpre);
        float4* recM2 = rec1 + M;
        float4* rec_a = recM2 + M;
        int*    csr_m = (int*)(rec_a + N_ATOMS);
        float*  cM    = (float*)(csr_m + M);

        zero_kernel<<<nblk, 256, 0, stream>>>(counts, N_ATOMS);
        countrec_kernel<<<nchunk, 256, 0, stream>>>(
            atom_idx, slot_idx, W, counts, rec1, M);
        scan1_kernel<<<nblk, SCAN_BLK, 0, stream>>>(counts, off, bsum, N_ATOMS);
        scan3_kernel<<<nblk, 256, 0, stream>>>(off, bsum, counts,
                                               cursor2, rec_a, N_ATOMS);
        fill2_kernel<<<nchunk, 256, 0, stream>>>(
            atom_idx, off, ang, scal, cursor2, csr_m, recM2, M);

        dim3 gm(nchunk, 8);
        mcontrib_kernel<<<gm, 256, 0, stream>>>(
            rec1, recM2, p1, p2, P, out_rot, cM, M);

        int abps = (N_ATOMS + 255) / 256;                // 391
        sum2_kernel<<<abps * BATCH, 256, 0, stream>>>(
            rec_a, csr_m, cM, out_atoms, M, abps);
        return;
    }

    // last resort: atomic scatter
    hipMemsetAsync(out_atoms, 0, (size_t)BATCH * N_ATOMS * 3 * sizeof(float), stream);
    int total = BATCH * M;
    backmap_fallback<<<(total + 255) / 256, 256, 0, stream>>>(
        P, p1, p2, W, ang, scal, slot_idx, atom_idx,
        out_atoms, out_rot, M);
}